// Round 1
// baseline (162.070 us; speedup 1.0000x reference)
//
#include <hip/hip_runtime.h>
#include <hip/hip_bf16.h>

// SemanticDecoder: mean = b@Wmu+bmu; s = b@Wsig+bsig; var = s*s;
// sample = mean + |s|*eps.  B=65536, K=64, D=300. All f32.
// Outputs concatenated: [sample(B*D), mean(B*D), var(B*D)].

#define B_ROWS 65536
#define K_DIM 64
#define D_DIM 300
#define ROWS_PER_BLOCK 128
#define THREADS 320   // 5 waves; threads 0..299 own one output column each

__global__ __launch_bounds__(THREADS) void sem_dec_kernel(
    const float* __restrict__ b,
    const float* __restrict__ Wmu,
    const float* __restrict__ bmu,
    const float* __restrict__ Wsig,
    const float* __restrict__ bsig,
    const float* __restrict__ eps,
    float* __restrict__ out)
{
    __shared__ float lds_b[ROWS_PER_BLOCK * K_DIM]; // 32 KB

    const int tid  = threadIdx.x;
    const int row0 = blockIdx.x * ROWS_PER_BLOCK;

    // ---- stage b[row0 : row0+128, 0:64] -> LDS, coalesced float4 ----
    {
        const float4* gb = reinterpret_cast<const float4*>(b + (size_t)row0 * K_DIM);
        float4* sb = reinterpret_cast<float4*>(lds_b);
        const int n4 = ROWS_PER_BLOCK * K_DIM / 4; // 2048
        for (int i = tid; i < n4; i += THREADS) sb[i] = gb[i];
    }
    __syncthreads();

    if (tid >= D_DIM) return;
    const int d = tid;

    // ---- both weight columns into VGPRs (coalesced across lanes) ----
    float wmu_r[K_DIM], wsig_r[K_DIM];
    #pragma unroll
    for (int k = 0; k < K_DIM; ++k) {
        wmu_r[k]  = Wmu[(size_t)k * D_DIM + d];
        wsig_r[k] = Wsig[(size_t)k * D_DIM + d];
    }
    const float bm = bmu[d];
    const float bs = bsig[d];

    const size_t BD = (size_t)B_ROWS * D_DIM;
    float* __restrict__ out_sample = out;
    float* __restrict__ out_mean   = out + BD;
    float* __restrict__ out_var    = out + 2 * BD;

    size_t ed = (size_t)row0 * D_DIM + d;

    // eps software pipeline: one 4-row group of lead (~1400 cy > HBM latency)
    float e0 = eps[ed];
    float e1 = eps[ed +     D_DIM];
    float e2 = eps[ed + 2 * D_DIM];
    float e3 = eps[ed + 3 * D_DIM];

    for (int rg = 0; rg < ROWS_PER_BLOCK; rg += 4) {
        const float f0 = e0, f1 = e1, f2 = e2, f3 = e3;
        if (rg + 4 < ROWS_PER_BLOCK) {
            const size_t p = ed + 4 * (size_t)D_DIM;
            e0 = eps[p];
            e1 = eps[p +     D_DIM];
            e2 = eps[p + 2 * D_DIM];
            e3 = eps[p + 3 * D_DIM];
        }
        #pragma unroll
        for (int j = 0; j < 4; ++j) {
            const float e = (j == 0) ? f0 : (j == 1) ? f1 : (j == 2) ? f2 : f3;
            const float4* b4p =
                reinterpret_cast<const float4*>(lds_b + (rg + j) * K_DIM);
            // 4 independent FMA chains -> full FMA issue rate from one wave
            float am0 = bm, am1 = 0.f, as0 = bs, as1 = 0.f;
            #pragma unroll
            for (int kk = 0; kk < K_DIM / 8; ++kk) {
                const float4 x = b4p[2 * kk];
                const float4 y = b4p[2 * kk + 1];
                am0 = fmaf(x.x, wmu_r[8*kk+0], am0); as0 = fmaf(x.x, wsig_r[8*kk+0], as0);
                am1 = fmaf(x.y, wmu_r[8*kk+1], am1); as1 = fmaf(x.y, wsig_r[8*kk+1], as1);
                am0 = fmaf(x.z, wmu_r[8*kk+2], am0); as0 = fmaf(x.z, wsig_r[8*kk+2], as0);
                am1 = fmaf(x.w, wmu_r[8*kk+3], am1); as1 = fmaf(x.w, wsig_r[8*kk+3], as1);
                am0 = fmaf(y.x, wmu_r[8*kk+4], am0); as0 = fmaf(y.x, wsig_r[8*kk+4], as0);
                am1 = fmaf(y.y, wmu_r[8*kk+5], am1); as1 = fmaf(y.y, wsig_r[8*kk+5], as1);
                am0 = fmaf(y.z, wmu_r[8*kk+6], am0); as0 = fmaf(y.z, wsig_r[8*kk+6], as0);
                am1 = fmaf(y.w, wmu_r[8*kk+7], am1); as1 = fmaf(y.w, wsig_r[8*kk+7], as1);
            }
            const float mean   = am0 + am1;
            const float s      = as0 + as1;
            const float var    = s * s;
            const float sample = fmaf(fabsf(s), e, mean);
            const size_t o = ed + (size_t)j * D_DIM;
            out_sample[o] = sample;
            out_mean[o]   = mean;
            out_var[o]    = var;
        }
        ed += 4 * (size_t)D_DIM;
    }
}

extern "C" void kernel_launch(void* const* d_in, const int* in_sizes, int n_in,
                              void* d_out, int out_size, void* d_ws, size_t ws_size,
                              hipStream_t stream) {
    const float* b    = (const float*)d_in[0];
    // d_in[1] = labels (unused by the reference outputs)
    const float* Wmu  = (const float*)d_in[2];
    const float* bmu  = (const float*)d_in[3];
    const float* Wsig = (const float*)d_in[4];
    const float* bsig = (const float*)d_in[5];
    const float* eps  = (const float*)d_in[6];
    float* out = (float*)d_out;

    dim3 grid(B_ROWS / ROWS_PER_BLOCK); // 512 blocks
    dim3 block(THREADS);
    hipLaunchKernelGGL(sem_dec_kernel, grid, block, 0, stream,
                       b, Wmu, bmu, bsig ? Wsig : Wsig, bsig, eps, out);
}

// Round 3
// 127.406 us; speedup vs baseline: 1.2721x; 1.2721x over previous
//
#include <hip/hip_runtime.h>
#include <hip/hip_bf16.h>

// SemanticDecoder: mean = b@Wmu+bmu; s = b@Wsig+bsig; var = s*s;
// sample = mean + |s|*eps.  B=65536, K=64, D=300. f32 in/out.
// Outputs concatenated: [sample(B*D), mean(B*D), var(B*D)].
//
// R3 = R2 with __fp16 vector types (cvt_pkrtz returns __fp16x2, which clang
// won't implicitly convert to _Float16x2). Design: weights packed f16 in
// VGPRs (64 regs for both matrices), b staged to LDS as packed f16,
// v_dot2_f32_f16 for 2 MACs/instr, 1024 blocks for occupancy.

#define B_ROWS 65536
#define K_DIM 64
#define D_DIM 300
#define ROWS_PER_BLOCK 64
#define THREADS 320   // 5 waves; threads 0..299 own one output column each

typedef __fp16 half2v __attribute__((ext_vector_type(2)));
typedef __fp16 half4v __attribute__((ext_vector_type(4)));
typedef __fp16 half8v __attribute__((ext_vector_type(8)));

__device__ __forceinline__ float dot2h(half2v a, half2v b, float c) {
#if __has_builtin(__builtin_amdgcn_fdot2)
    return __builtin_amdgcn_fdot2(a, b, c, false);
#else
    return fmaf((float)a[0], (float)b[0], fmaf((float)a[1], (float)b[1], c));
#endif
}

__global__ __launch_bounds__(THREADS, 4) void sem_dec_kernel(
    const float* __restrict__ b,
    const float* __restrict__ Wmu,
    const float* __restrict__ bmu,
    const float* __restrict__ Wsig,
    const float* __restrict__ bsig,
    const float* __restrict__ eps,
    float* __restrict__ out)
{
    __shared__ __fp16 lds_bh[ROWS_PER_BLOCK * K_DIM]; // 8 KB packed f16

    const int tid  = threadIdx.x;
    const int row0 = blockIdx.x * ROWS_PER_BLOCK;

    // ---- stage b[row0:row0+64, 0:64] -> LDS as f16, coalesced float4 in ----
    {
        const float4* gb = reinterpret_cast<const float4*>(b + (size_t)row0 * K_DIM);
        const int n4 = ROWS_PER_BLOCK * K_DIM / 4; // 1024
        for (int i = tid; i < n4; i += THREADS) {
            float4 v = gb[i];
            half2v p0 = __builtin_amdgcn_cvt_pkrtz(v.x, v.y);
            half2v p1 = __builtin_amdgcn_cvt_pkrtz(v.z, v.w);
            half4v p = __builtin_shufflevector(p0, p1, 0, 1, 2, 3);
            *reinterpret_cast<half4v*>(&lds_bh[4 * i]) = p; // ds_write_b64
        }
    }
    __syncthreads();

    if (tid >= D_DIM) return;
    const int d = tid;

    // ---- both weight columns -> packed f16 VGPRs (64 regs total) ----
    half2v wmu_h[K_DIM / 2], wsig_h[K_DIM / 2];
    #pragma unroll
    for (int k = 0; k < K_DIM / 2; ++k) {
        float a0 = Wmu[(size_t)(2 * k) * D_DIM + d];
        float a1 = Wmu[(size_t)(2 * k + 1) * D_DIM + d];
        wmu_h[k] = __builtin_amdgcn_cvt_pkrtz(a0, a1);
        float c0 = Wsig[(size_t)(2 * k) * D_DIM + d];
        float c1 = Wsig[(size_t)(2 * k + 1) * D_DIM + d];
        wsig_h[k] = __builtin_amdgcn_cvt_pkrtz(c0, c1);
    }
    const float bm = bmu[d];
    const float bs = bsig[d];

    const size_t BD = (size_t)B_ROWS * D_DIM;
    float* __restrict__ out_sample = out;
    float* __restrict__ out_mean   = out + BD;
    float* __restrict__ out_var    = out + 2 * BD;

    size_t ed = (size_t)row0 * D_DIM + d;

    // eps software pipeline: one 4-row group of lead
    float e0 = eps[ed];
    float e1 = eps[ed +     D_DIM];
    float e2 = eps[ed + 2 * D_DIM];
    float e3 = eps[ed + 3 * D_DIM];

    for (int rg = 0; rg < ROWS_PER_BLOCK; rg += 4) {
        const float f0 = e0, f1 = e1, f2 = e2, f3 = e3;
        if (rg + 4 < ROWS_PER_BLOCK) {
            const size_t p = ed + 4 * (size_t)D_DIM;
            e0 = eps[p];
            e1 = eps[p +     D_DIM];
            e2 = eps[p + 2 * D_DIM];
            e3 = eps[p + 3 * D_DIM];
        }
        #pragma unroll
        for (int j = 0; j < 4; ++j) {
            const float e = (j == 0) ? f0 : (j == 1) ? f1 : (j == 2) ? f2 : f3;
            const half8v* bp =
                reinterpret_cast<const half8v*>(&lds_bh[(rg + j) * K_DIM]);
            // 4 independent dot chains (2 mu, 2 sig)
            float am0 = bm, am1 = 0.f, as0 = bs, as1 = 0.f;
            #pragma unroll
            for (int kk = 0; kk < K_DIM / 8; ++kk) {   // 8 x ds_read_b128
                half8v r = bp[kk];
                half2v q0 = __builtin_shufflevector(r, r, 0, 1);
                half2v q1 = __builtin_shufflevector(r, r, 2, 3);
                half2v q2 = __builtin_shufflevector(r, r, 4, 5);
                half2v q3 = __builtin_shufflevector(r, r, 6, 7);
                am0 = dot2h(q0, wmu_h[4*kk+0], am0);
                am1 = dot2h(q1, wmu_h[4*kk+1], am1);
                as0 = dot2h(q0, wsig_h[4*kk+0], as0);
                as1 = dot2h(q1, wsig_h[4*kk+1], as1);
                am0 = dot2h(q2, wmu_h[4*kk+2], am0);
                am1 = dot2h(q3, wmu_h[4*kk+3], am1);
                as0 = dot2h(q2, wsig_h[4*kk+2], as0);
                as1 = dot2h(q3, wsig_h[4*kk+3], as1);
            }
            const float mean   = am0 + am1;
            const float s      = as0 + as1;
            const float var    = s * s;
            const float sample = fmaf(fabsf(s), e, mean);
            const size_t o = ed + (size_t)j * D_DIM;
            out_sample[o] = sample;
            out_mean[o]   = mean;
            out_var[o]    = var;
        }
        ed += 4 * (size_t)D_DIM;
    }
}

extern "C" void kernel_launch(void* const* d_in, const int* in_sizes, int n_in,
                              void* d_out, int out_size, void* d_ws, size_t ws_size,
                              hipStream_t stream) {
    const float* b    = (const float*)d_in[0];
    // d_in[1] = labels (unused by the reference outputs)
    const float* Wmu  = (const float*)d_in[2];
    const float* bmu  = (const float*)d_in[3];
    const float* Wsig = (const float*)d_in[4];
    const float* bsig = (const float*)d_in[5];
    const float* eps  = (const float*)d_in[6];
    float* out = (float*)d_out;

    dim3 grid(B_ROWS / ROWS_PER_BLOCK); // 1024 blocks
    dim3 block(THREADS);
    hipLaunchKernelGGL(sem_dec_kernel, grid, block, 0, stream,
                       b, Wmu, bmu, Wsig, bsig, eps, out);
}